// Round 3
// baseline (380.955 us; speedup 1.0000x reference)
//
#include <hip/hip_runtime.h>

// MultiScaleSubsequenceExtractor: masked sliding-window means.
// B=128, L=1024, D=128, windows {4,8,16,32}; out rows/batch = 1021+1017+1009+993 = 4040.
// Memory-bound: ~265 MB write + ~65 MB read -> ~53 us kernel floor at 6.3 TB/s.
// Ladder (kernel-dispatch est., bench = kernel + ~233 us fixed fill/graph overhead):
//  R2: LDS-stage TILE=64 + NT stores/loads            ~80 us (bench 313)
//  R3: D-split 6 blocks/CU                             169 us (occupancy NOT the limiter;
//      WRITE_SIZE 487 MB was R3-pattern-specific amp)
//  R4: plain stores + cached loads + XCD swizzle       ~94 us (bench 327)
//  All three run at 3.8-4.1 TB/s vs fill's 6.2 -> structural limit: stage->barrier->store
//  phase serialization keeps only one HBM direction busy at a time.
// R5: BARRIER-FREE STREAMING. Drop LDS data staging; per-thread running window sums with
//     5 direct global taps/position (4 are L1-hot from the thread's own warm-up; input is
//     64 MB = L3-resident). LDS only for maskf + reciprocals (2.7 KB). Every wave issues
//     loads and NT stores continuously -> both HBM directions always in flight.

namespace {
constexpr int kB    = 128;
constexpr int kL    = 1024;
constexpr int kD    = 128;
constexpr int kD4   = kD / 4;        // float4 per row = 32
constexpr int ROUT  = 4040;          // output rows per batch
constexpr int OFF4  = 0;
constexpr int OFF8  = 1021;
constexpr int OFF16 = 2038;          // 1021 + 1017
constexpr int OFF32 = 3047;          // 2038 + 1009
constexpr int BPOS  = 128;           // positions per block (8 teams x 16)
constexpr int TP    = 16;            // positions per 32-lane team
constexpr int NCH   = kL / BPOS;     // 8 chunks per batch
}

typedef float v4f __attribute__((ext_vector_type(4)));

__device__ __forceinline__ void nt_store(float4* p, const float4& v) {
    v4f x;
    x.x = v.x; x.y = v.y; x.z = v.z; x.w = v.w;
    __builtin_nontemporal_store(x, reinterpret_cast<v4f*>(p));
}
__device__ __forceinline__ float4 f4zero() { return make_float4(0.f, 0.f, 0.f, 0.f); }

// a += x * m
__device__ __forceinline__ void fma4(float4& a, const float4& x, float m) {
    a.x = fmaf(x.x, m, a.x); a.y = fmaf(x.y, m, a.y);
    a.z = fmaf(x.z, m, a.z); a.w = fmaf(x.w, m, a.w);
}
// a += xi*mi - xo*mo
__device__ __forceinline__ void slide4m(float4& a, const float4& xi, float mi,
                                        const float4& xo, float mo) {
    a.x = fmaf(xi.x, mi, fmaf(-xo.x, mo, a.x));
    a.y = fmaf(xi.y, mi, fmaf(-xo.y, mo, a.y));
    a.z = fmaf(xi.z, mi, fmaf(-xo.z, mo, a.z));
    a.w = fmaf(xi.w, mi, fmaf(-xo.w, mo, a.w));
}
__device__ __forceinline__ float4 scale4(const float4& v, float s) {
    return make_float4(v.x * s, v.y * s, v.z * s, v.w * s);
}

__global__ __launch_bounds__(256, 4)
void msse_kernel(const float* __restrict__ emb,
                 const int*   __restrict__ mask,
                 float*       __restrict__ out) {
    __shared__ float s_maskf[BPOS + 32];   // 160 mask floats for rows [P0, P0+160)
    __shared__ float s_inv[4][BPOS];       // 1/clip(count,1) per window per position

    const int b  = blockIdx.y;
    const int P0 = blockIdx.x * BPOS;
    const int t  = threadIdx.x;

    // ---- tiny prologue: mask floats + per-position reciprocals ----
    if (t < BPOS + 32) {
        const int row = P0 + t;
        s_maskf[t] = (row < kL) ? (float)mask[b * kL + row] : 0.f;
    }
    __syncthreads();
    if (t < BPOS) {
        float c = 0.f, c4 = 0.f, c8 = 0.f, c16 = 0.f;
        #pragma unroll
        for (int j = 0; j < 32; ++j) {
            c += s_maskf[t + j];
            if (j == 3)  c4  = c;
            if (j == 7)  c8  = c;
            if (j == 15) c16 = c;
        }
        s_inv[0][t] = 1.f / fmaxf(c4,  1.f);
        s_inv[1][t] = 1.f / fmaxf(c8,  1.f);
        s_inv[2][t] = 1.f / fmaxf(c16, 1.f);
        s_inv[3][t] = 1.f / fmaxf(c,   1.f);
    }
    __syncthreads();
    // ---- no barriers past this point: pure streaming ----

    const int lane = t & 31;          // float4 column
    const int team = t >> 5;          // 0..7, each team owns 16 positions
    const int l0   = team * TP;       // local position base
    const int p0   = P0 + l0;         // global position base

    const float4* g = reinterpret_cast<const float4*>(emb)
                    + (size_t)b * kL * kD4 + lane;   // row r -> g[r*kD4]

    // ---- warm-up: build initial sums for position p0 (rows p0..p0+31) ----
    float4 s4, s8, s16, s32;
    {
        float4 a = f4zero(), t4 = a, t8 = a, t16 = a;
        #pragma unroll
        for (int j = 0; j < 32; ++j) {
            const int r = p0 + j;
            const float4 x = (r < kL) ? g[(size_t)r * kD4] : f4zero();
            fma4(a, x, s_maskf[l0 + j]);
            if (j == 3)  t4  = a;
            if (j == 7)  t8  = a;
            if (j == 15) t16 = a;
        }
        s4 = t4; s8 = t8; s16 = t16; s32 = a;
    }

    float4* ob = reinterpret_cast<float4*>(out) + (size_t)b * ROUT * kD4 + lane;

    // ---- 16 streaming steps: 4 NT stores + 5 tap loads + slides per step ----
    #pragma unroll
    for (int p = 0; p < TP; ++p) {
        const int li = l0 + p;        // local position (index into s_maskf / s_inv)
        const int i  = P0 + li;       // global position

        if (i <= kL - 4)  nt_store(&ob[(size_t)(OFF4  + i) * kD4], scale4(s4,  s_inv[0][li]));
        if (i <= kL - 8)  nt_store(&ob[(size_t)(OFF8  + i) * kD4], scale4(s8,  s_inv[1][li]));
        if (i <= kL - 16) nt_store(&ob[(size_t)(OFF16 + i) * kD4], scale4(s16, s_inv[2][li]));
        if (i <= kL - 32) nt_store(&ob[(size_t)(OFF32 + i) * kD4], scale4(s32, s_inv[3][li]));

        // advance to position i+1: taps i, i+4, i+8, i+16 are L1-hot (own warm-up rows);
        // i+32 is the one fresh row. (Compiler DCEs the dead final slide.)
        const float4 x0 = g[(size_t)i * kD4];
        const float4 xa = (i + 4  < kL) ? g[(size_t)(i + 4)  * kD4] : f4zero();
        const float4 xb = (i + 8  < kL) ? g[(size_t)(i + 8)  * kD4] : f4zero();
        const float4 xc = (i + 16 < kL) ? g[(size_t)(i + 16) * kD4] : f4zero();
        const float4 xd = (i + 32 < kL) ? g[(size_t)(i + 32) * kD4] : f4zero();
        const float m0 = s_maskf[li];
        const float ma = s_maskf[li + 4];
        const float mb = s_maskf[li + 8];
        const float mc = s_maskf[li + 16];
        const float md = s_maskf[li + 32];
        slide4m(s4,  xa, ma, x0, m0);
        slide4m(s8,  xb, mb, x0, m0);
        slide4m(s16, xc, mc, x0, m0);
        slide4m(s32, xd, md, x0, m0);
    }
}

extern "C" void kernel_launch(void* const* d_in, const int* in_sizes, int n_in,
                              void* d_out, int out_size, void* d_ws, size_t ws_size,
                              hipStream_t stream) {
    const float* emb  = (const float*)d_in[0];
    const int*   mask = (const int*)d_in[1];
    float*       out  = (float*)d_out;

    dim3 grid(NCH, kB);   // (8, 128) = 1024 blocks, 4/CU, 16 waves/CU
    dim3 block(256);
    msse_kernel<<<grid, block, 0, stream>>>(emb, mask, out);
}

// Round 4
// 307.422 us; speedup vs baseline: 1.2392x; 1.2392x over previous
//
#include <hip/hip_runtime.h>

// MultiScaleSubsequenceExtractor: masked sliding-window means.
// B=128, L=1024, D=128, windows {4,8,16,32}; out rows/batch = 1021+1017+1009+993 = 4040.
// Memory-bound: ~265 MB write + reads -> ~42-58 us kernel floor at 6.3 TB/s.
// Ladder (kernel est. = bench - ~233 us fixed overhead; R3's kernel measured directly):
//  R2: LDS-stage TILE=64, NT loads + NT stores        ~80 us (bench 313)  <- base
//  R3: D-split 6 blocks/CU                             169 us (occupancy not the limiter)
//  R4: cached loads + PLAIN stores + swizzle           ~94 us (bench 327)
//  R5: no-LDS streaming, 5 global taps/pos             ~148 us (latency-bound; dead end)
// R6 theory: input (64 MB) is L3-resident ONLY if (a) loads allocate (not NT) and
//  (b) the 265 MB/iter output stream does NOT cycle L3 (stores NT). R2 violated (a),
//  R4 violated (b). This round: cached staging loads + NT stores — single variable
//  flip of the staging-load flavor vs the 313 us R2 baseline.

namespace {
constexpr int kB    = 128;
constexpr int kL    = 1024;
constexpr int kD    = 128;
constexpr int kD4   = kD / 4;        // float4 per row = 32
constexpr int TILE  = 64;            // output positions per block
constexpr int HALO  = 32;            // max window size
constexpr int ROWS  = TILE + HALO;   // 96 staged rows
constexpr int ROUT  = 4040;          // output rows per batch
constexpr int OFF4  = 0;
constexpr int OFF8  = 1021;
constexpr int OFF16 = 2038;          // 1021 + 1017
constexpr int OFF32 = 3047;          // 2038 + 1009
}

typedef float v4f __attribute__((ext_vector_type(4)));

__device__ __forceinline__ void nt_store(float4* p, const float4& v) {
    v4f x;
    x.x = v.x; x.y = v.y; x.z = v.z; x.w = v.w;
    __builtin_nontemporal_store(x, reinterpret_cast<v4f*>(p));
}

__device__ __forceinline__ void acc4(float4& a, const float4& x) {
    a.x += x.x; a.y += x.y; a.z += x.z; a.w += x.w;
}
__device__ __forceinline__ void slide4(float4& a, const float4& xin, const float4& xout) {
    a.x += xin.x - xout.x; a.y += xin.y - xout.y;
    a.z += xin.z - xout.z; a.w += xin.w - xout.w;
}
__device__ __forceinline__ float4 scale4(const float4& v, float s) {
    return make_float4(v.x * s, v.y * s, v.z * s, v.w * s);
}

__global__ __launch_bounds__(256)
void msse_kernel(const float* __restrict__ emb,
                 const int*   __restrict__ mask,
                 float*       __restrict__ out) {
    __shared__ float4 s_data[ROWS * kD4];   // 48 KB: masked embeddings, row-major
    __shared__ float  s_mask[ROWS];
    __shared__ float  s_inv[4][TILE];       // 1/clip(count,1) per window per position

    const int b  = blockIdx.y;
    const int i0 = blockIdx.x * TILE;
    const int t  = threadIdx.x;

    // ---- stage masked input tile (rows [i0, i0+96)) into LDS, float4 coalesced ----
    // CACHED loads: input is 64 MB -> L3-resident across iterations (NT stores below
    // keep the output stream from cycling L3). This is the only change vs the R2 base.
    const float4* gsrc = reinterpret_cast<const float4*>(emb) + (size_t)b * kL * kD4;
    #pragma unroll
    for (int k = 0; k < (ROWS * kD4) / 256; ++k) {   // 3072/256 = 12 iters
        const int f    = t + k * 256;
        const int row  = f >> 5;                     // 32 float4 per row
        const int grow = i0 + row;
        float4 v = make_float4(0.f, 0.f, 0.f, 0.f);
        float  m = 0.f;
        if (grow < kL) {
            m = (float)mask[b * kL + grow];
            v = gsrc[(size_t)grow * kD4 + (f & 31)];
            v.x *= m; v.y *= m; v.z *= m; v.w *= m;
        }
        s_data[f] = v;
        if ((f & 31) == 0) s_mask[row] = m;
    }
    __syncthreads();

    // ---- per-position window-count reciprocals (threads 0..63) ----
    if (t < TILE) {
        float c = 0.f, c4 = 0.f, c8 = 0.f, c16 = 0.f;
        #pragma unroll
        for (int j = 0; j < 32; ++j) {
            c += s_mask[t + j];
            if (j == 3)  c4  = c;
            if (j == 7)  c8  = c;
            if (j == 15) c16 = c;
        }
        s_inv[0][t] = 1.f / fmaxf(c4,  1.f);
        s_inv[1][t] = 1.f / fmaxf(c8,  1.f);
        s_inv[2][t] = 1.f / fmaxf(c16, 1.f);
        s_inv[3][t] = 1.f / fmaxf(c,   1.f);
    }
    __syncthreads();

    // ---- sliding-window sums: thread = (float4 column, 8-position strip) ----
    const int lane  = t & 31;        // float4 column index
    const int strip = t >> 5;        // 0..7
    const int base  = strip * 8;     // first local position of strip

    const float4* col = s_data + lane;   // row stride = kD4

    float4 s4, s8, s16, s32;
    {
        float4 a  = make_float4(0.f, 0.f, 0.f, 0.f);
        float4 t4 = a, t8 = a, t16 = a;
        #pragma unroll
        for (int j = 0; j < 32; ++j) {
            acc4(a, col[(base + j) * kD4]);
            if (j == 3)  t4  = a;
            if (j == 7)  t8  = a;
            if (j == 15) t16 = a;
        }
        s4 = t4; s8 = t8; s16 = t16; s32 = a;
    }

    float4* outb = reinterpret_cast<float4*>(out) + (size_t)b * ROUT * kD4 + lane;

    #pragma unroll
    for (int p = 0; p < 8; ++p) {
        const int il = base + p;
        const int i  = i0 + il;

        if (i <= kL - 4)  nt_store(outb + (size_t)(OFF4  + i) * kD4, scale4(s4,  s_inv[0][il]));
        if (i <= kL - 8)  nt_store(outb + (size_t)(OFF8  + i) * kD4, scale4(s8,  s_inv[1][il]));
        if (i <= kL - 16) nt_store(outb + (size_t)(OFF16 + i) * kD4, scale4(s16, s_inv[2][il]));
        if (i <= kL - 32) nt_store(outb + (size_t)(OFF32 + i) * kD4, scale4(s32, s_inv[3][il]));

        // advance all windows to position i+1 (max row = base+7+32 = 95, in range)
        const float4 x0 = col[(il)      * kD4];
        const float4 xa = col[(il + 4)  * kD4];
        const float4 xb = col[(il + 8)  * kD4];
        const float4 xc = col[(il + 16) * kD4];
        const float4 xd = col[(il + 32) * kD4];
        slide4(s4,  xa, x0);
        slide4(s8,  xb, x0);
        slide4(s16, xc, x0);
        slide4(s32, xd, x0);
    }
}

extern "C" void kernel_launch(void* const* d_in, const int* in_sizes, int n_in,
                              void* d_out, int out_size, void* d_ws, size_t ws_size,
                              hipStream_t stream) {
    const float* emb  = (const float*)d_in[0];
    const int*   mask = (const int*)d_in[1];
    float*       out  = (float*)d_out;

    dim3 grid((kL + TILE - 1) / TILE, kB);   // (16, 128) = 2048 blocks
    dim3 block(256);
    msse_kernel<<<grid, block, 0, stream>>>(emb, mask, out);
}